// Round 1
// 272.659 us; speedup vs baseline: 1.0070x; 1.0070x over previous
//
#include <hip/hip_runtime.h>
#include <hip/hip_bf16.h>

#define D 128
#define LR 0.025f
#define NCE_BIAS 11.512925464970229f      // log(100000)
#define NCE_NEG_BIAS 9.903487552536127f   // log(100000/5)
#define LUT_SIZE 1202

__device__ __forceinline__ float wave_allreduce(float x) {
    #pragma unroll
    for (int m = 32; m >= 1; m >>= 1) x += __shfl_xor(x, m, 64);
    return x;
}

// Analytic stand-in for the reference's LUT sigmoid (centered quantization err <=1.25e-3).
__device__ __forceinline__ float fast_sig(float x) {
    x = fminf(fmaxf(x, -6.0f), 6.0f) - 0.005f;
    float e = __expf(-x);
    return __builtin_amdgcn_rcpf(1.0f + e);
}

__device__ __forceinline__ float fast_sig_lut(float s, const float* __restrict__ lut) {
    s = fminf(fmaxf(s, -6.0f), 6.0f);
    int idx = (int)floorf((s + 6.01f) / 0.01f);
    idx = min(max(idx, 0), LUT_SIZE - 1);
    return lut[idx];
}

__device__ __forceinline__ unsigned int bf16_rne(float f) {
    unsigned int u = __float_as_uint(f);
    return (u + 0x7FFFu + ((u >> 16) & 1u)) >> 16;
}

// ---------------- W -> bf16 shadow ----------------
__global__ __launch_bounds__(256) void conv_kernel(
    const float* __restrict__ W, unsigned short* __restrict__ w16, int n32)
{
    int g = blockIdx.x * 256 + threadIdx.x;
    if (g >= n32) return;
    float4 v = ((const float4*)W)[g];
    uint2 h;
    h.x = bf16_rne(v.x) | (bf16_rne(v.y) << 16);
    h.y = bf16_rne(v.z) | (bf16_rne(v.w) << 16);
    ((uint2*)w16)[g] = h;
}

// ---------------- CSR build ----------------
// cnt2[i] = {pos_degree, neg_degree}. Pos pair t: ONE 64-bit atomic bumps both
// fields of u (pos +1, neg +NEG — idx_neg_u = repeat(idx_pos_u, NEG)).
__global__ __launch_bounds__(256) void hist_kernel(
    const int* __restrict__ ipu, const int* __restrict__ ipv,
    const int* __restrict__ inv,
    int Np, int Nn, int NEG, int2* __restrict__ cnt2)
{
    int t = blockIdx.x * 256 + threadIdx.x;
    if (t < Np) {
        atomicAdd((unsigned long long*)&cnt2[ipu[t]],
                  1ull + ((unsigned long long)NEG << 32));
        atomicAdd(&cnt2[ipv[t]].x, 1);
    } else if (t < Np + Nn) {
        int k = t - Np;
        atomicAdd(&cnt2[inv[k]].y, 1);
    }
}

// fused dual exclusive scan (pos & neg fields in one pass)
__global__ __launch_bounds__(256) void scan_local2(
    const int2* __restrict__ cnt2, int* __restrict__ off_p, int* __restrict__ off_n,
    int* __restrict__ bsp, int* __restrict__ bsn, int n)
{
    __shared__ int shp[256], shn[256];
    int g = blockIdx.x * 256 + threadIdx.x;
    int2 x = (g < n) ? cnt2[g] : make_int2(0, 0);
    shp[threadIdx.x] = x.x;
    shn[threadIdx.x] = x.y;
    __syncthreads();
    #pragma unroll
    for (int d = 1; d < 256; d <<= 1) {
        int tp = (threadIdx.x >= d) ? shp[threadIdx.x - d] : 0;
        int tn = (threadIdx.x >= d) ? shn[threadIdx.x - d] : 0;
        __syncthreads();
        shp[threadIdx.x] += tp;
        shn[threadIdx.x] += tn;
        __syncthreads();
    }
    if (g < n) {
        off_p[g] = shp[threadIdx.x] - x.x;
        off_n[g] = shn[threadIdx.x] - x.y;
    }
    if (threadIdx.x == 255) {
        bsp[blockIdx.x] = shp[255];
        bsn[blockIdx.x] = shn[255];
    }
}

__device__ __forceinline__ void scan_one(int* b, int nb) {
    __shared__ int sh[256];
    __shared__ int carry_s;
    if (threadIdx.x == 0) carry_s = 0;
    __syncthreads();
    for (int c = 0; c < nb; c += 256) {
        int i = c + threadIdx.x;
        int x = (i < nb) ? b[i] : 0;
        sh[threadIdx.x] = x;
        __syncthreads();
        for (int d = 1; d < 256; d <<= 1) {
            int t = (threadIdx.x >= d) ? sh[threadIdx.x - d] : 0;
            __syncthreads();
            sh[threadIdx.x] += t;
            __syncthreads();
        }
        int carry = carry_s;
        if (i < nb) b[i] = sh[threadIdx.x] - x + carry;
        __syncthreads();
        if (threadIdx.x == 0) carry_s = carry + sh[255];
        __syncthreads();
    }
}

__global__ __launch_bounds__(256) void scan_bsum2(int* __restrict__ bsp, int* __restrict__ bsn, int nb)
{
    scan_one(bsp, nb);
    __syncthreads();
    scan_one(bsn, nb);
}

__global__ __launch_bounds__(256) void add_base2(
    int* __restrict__ off_p, int* __restrict__ off_n, int2* __restrict__ cur2,
    const int* __restrict__ bsp, const int* __restrict__ bsn, int n)
{
    int g = blockIdx.x * 256 + threadIdx.x;
    if (g < n) {
        int vp = off_p[g] + bsp[blockIdx.x];
        int vn = off_n[g] + bsn[blockIdx.x];
        off_p[g] = vp;
        off_n[g] = vn;
        cur2[g] = make_int2(vp, vn);
    }
}

// pos pair t: ONE 64-bit atomic reserves the u-side pos slot AND NEG contiguous
// neg slots; neg partners written contiguously.
__global__ __launch_bounds__(256) void fill_kernel(
    const int* __restrict__ ipu, const int* __restrict__ ipv,
    const int* __restrict__ inu, const int* __restrict__ inv,
    int Np, int Nn, int NEG,
    int2* __restrict__ cur2, int* __restrict__ ent_p, int* __restrict__ ent_n)
{
    int t = blockIdx.x * 256 + threadIdx.x;
    if (t < Np) {
        int u = ipu[t], v = ipv[t];
        unsigned long long pk = atomicAdd((unsigned long long*)&cur2[u],
                                          1ull + ((unsigned long long)NEG << 32));
        int slot_pu = (int)(pk & 0xFFFFFFFFull);
        int slot_nu = (int)(pk >> 32);
        ent_p[slot_pu] = v;
        for (int j = 0; j < NEG; ++j)
            ent_n[slot_nu + j] = inv[(size_t)NEG * t + j];
        ent_p[atomicAdd(&cur2[v].x, 1)] = u;
    } else if (t < Np + Nn) {
        int k = t - Np;
        ent_n[atomicAdd(&cur2[inv[k]].y, 1)] = inu[k];
    }
}

// ---------------- pull update (software-pipelined) ----------------
// Half-wave per node (32 lanes x float4 base). Partners are bf16 (256B rows).
// Entries prefetched 2 groups ahead; partner rows 1 group ahead (8 loads in flight).
//
// Reduction restructure (this round): the 4 per-group dots are reduced with a
// select-exchange butterfly (value count halves at xor16 and xor8 stages)
// instead of 4 independent 5-stage butterflies: 6 shfl + 6 add + 6 sel
// replaces 20 shfl + 20 add. Each lane class (bits 3,4 of hl) then holds the
// FULL sum of exactly one dot, so the clamp/exp/rcp score is evaluated ONCE
// per lane (was 4x), and 3 shfl + 8 sel broadcast the 4 scores back.
// The xor pairing order (16,8,4,2,1) and accumulation order are identical to
// the previous version => bit-identical results.
template<bool EMIT16>
__global__ __launch_bounds__(256) void update_kernel(
    const float* __restrict__ baseSrc,
    const unsigned short* __restrict__ partnerH,
    float* __restrict__ dst, unsigned short* __restrict__ dst16,
    const int* __restrict__ offArr, const int* __restrict__ endArr2, int comp,
    const int* __restrict__ entries, int N, float bias, float cpos)
{
    int gtid = blockIdx.x * 256 + threadIdx.x;
    int node = gtid >> 5;
    int hl   = threadIdx.x & 31;
    if (node >= N) return;

    const bool b3 = (hl & 8) != 0;
    const bool b4 = (hl & 16) != 0;
    const int i_lane = (hl >> 3) & 3;   // which entry's dot this lane owns post-reduce

    float4 base = ((const float4*)baseSrc)[(size_t)node * 32 + hl];
    float ax = 0.0f, ay = 0.0f, az = 0.0f, aw = 0.0f;

    int beg = offArr[node];
    int len = endArr2[2 * node + comp] - beg;
    const uint2* ph = (const uint2*)partnerH;

    if (len > 0) {
        int gcount = (len + 3) >> 2;
        int en[4];
        uint2 rc[4];
        #pragma unroll
        for (int i = 0; i < 4; ++i) {
            int t = min(i, len - 1);
            rc[i] = ph[(size_t)entries[beg + t] * 32 + hl];
        }
        #pragma unroll
        for (int i = 0; i < 4; ++i) {
            int t = min(4 + i, len - 1);
            en[i] = entries[beg + t];
        }
        for (int g = 0; g < gcount; ++g) {
            uint2 rn[4];
            #pragma unroll
            for (int i = 0; i < 4; ++i) rn[i] = ph[(size_t)en[i] * 32 + hl];
            int en2[4];
            #pragma unroll
            for (int i = 0; i < 4; ++i) {
                int t = (g + 2) * 4 + i;
                t = (t < len) ? t : (len - 1);
                en2[i] = entries[beg + t];
            }
            float4 r[4];
            float d[4];
            #pragma unroll
            for (int i = 0; i < 4; ++i) {
                r[i].x = __uint_as_float(rc[i].x << 16);
                r[i].y = __uint_as_float(rc[i].x & 0xFFFF0000u);
                r[i].z = __uint_as_float(rc[i].y << 16);
                r[i].w = __uint_as_float(rc[i].y & 0xFFFF0000u);
                d[i] = r[i].x * base.x + r[i].y * base.y + r[i].z * base.z + r[i].w * base.w;
            }
            // ---- select-exchange multi-reduce (same xor tree as before) ----
            // stage xor16: lo lanes keep entries {0,1}, hi lanes keep {2,3}
            float y0 = b4 ? d[0] : d[2];
            float y1 = b4 ? d[1] : d[3];
            y0 = __shfl_xor(y0, 16, 64);
            y1 = __shfl_xor(y1, 16, 64);
            float pa = b4 ? (d[2] + y0) : (d[0] + y0);
            float pb = b4 ? (d[3] + y1) : (d[1] + y1);
            // stage xor8: b3=0 keeps first of pair, b3=1 keeps second
            float y2 = b3 ? pa : pb;
            y2 = __shfl_xor(y2, 8, 64);
            float cc = b3 ? (pb + y2) : (pa + y2);
            // stages xor4,2,1: plain butterfly within the 8-lane class
            cc += __shfl_xor(cc, 4, 64);
            cc += __shfl_xor(cc, 2, 64);
            cc += __shfl_xor(cc, 1, 64);
            // lane class (b4,b3) now holds the FULL dot of entry i_lane = 2*b4+b3

            // ---- one score per lane (was 4x per lane) ----
            float s = (g * 4 + i_lane < len)
                        ? (cpos - fast_sig(cc - bias)) * LR : 0.0f;

            // ---- broadcast 4 scores to all lanes ----
            float t8  = __shfl_xor(s, 8, 64);    // entry 2*b4 + !b3
            float t16 = __shfl_xor(s, 16, 64);   // entry 2*!b4 + b3
            float t24 = __shfl_xor(t8, 16, 64);  // entry 2*!b4 + !b3
            float p  = b3 ? t8  : s;     // entry 2*b4 + 0
            float q  = b3 ? s   : t8;    // entry 2*b4 + 1
            float p2 = b3 ? t24 : t16;   // entry 2*!b4 + 0
            float q2 = b3 ? t16 : t24;   // entry 2*!b4 + 1
            float se[4];
            se[0] = b4 ? p2 : p;
            se[1] = b4 ? q2 : q;
            se[2] = b4 ? p  : p2;
            se[3] = b4 ? q  : q2;

            #pragma unroll
            for (int i = 0; i < 4; ++i) {
                ax += se[i] * r[i].x;
                ay += se[i] * r[i].y;
                az += se[i] * r[i].z;
                aw += se[i] * r[i].w;
            }
            #pragma unroll
            for (int i = 0; i < 4; ++i) { rc[i] = rn[i]; en[i] = en2[i]; }
        }
    }
    float4 o = make_float4(base.x + ax, base.y + ay, base.z + az, base.w + aw);
    ((float4*)dst)[(size_t)node * 32 + hl] = o;
    if (EMIT16) {
        uint2 h;
        h.x = bf16_rne(o.x) | (bf16_rne(o.y) << 16);
        h.y = bf16_rne(o.z) | (bf16_rne(o.w) << 16);
        ((uint2*)dst16)[(size_t)node * 32 + hl] = h;
    }
}

// ---------------- fallback scatter path (round-1, known-good) ----------------
__global__ __launch_bounds__(256) void pos_kernel(
    const float* __restrict__ Worig, float* __restrict__ W,
    const float* __restrict__ lut,
    const int* __restrict__ idx_u, const int* __restrict__ idx_v, int n)
{
    int wave = (int)((blockIdx.x * blockDim.x + threadIdx.x) >> 6);
    int lane = threadIdx.x & 63;
    if (wave >= n) return;
    int u = idx_u[wave];
    int v = idx_v[wave];
    float2 eu = ((const float2*)(Worig + (size_t)u * D))[lane];
    float2 ev = ((const float2*)(Worig + (size_t)v * D))[lane];
    float dot = wave_allreduce(eu.x * ev.x + eu.y * ev.y);
    float s = (1.0f - fast_sig_lut(dot - NCE_BIAS, lut)) * LR;
    float* wu = W + (size_t)u * D;
    float* wv = W + (size_t)v * D;
    atomicAdd(&wu[2 * lane],     s * ev.x);
    atomicAdd(&wu[2 * lane + 1], s * ev.y);
    atomicAdd(&wv[2 * lane],     s * eu.x);
    atomicAdd(&wv[2 * lane + 1], s * eu.y);
}

__global__ __launch_bounds__(256) void neg_kernel(
    const float* __restrict__ Wsnap, float* __restrict__ W,
    const float* __restrict__ lut,
    const int* __restrict__ idx_u, const int* __restrict__ idx_v, int n, int neg)
{
    int wave = (int)((blockIdx.x * blockDim.x + threadIdx.x) >> 6);
    int lane = threadIdx.x & 63;
    if (wave >= n) return;
    int u = idx_u[wave * neg];
    float2 eu = ((const float2*)(Wsnap + (size_t)u * D))[lane];
    float dux = 0.0f, duy = 0.0f;
    for (int j = 0; j < neg; ++j) {
        int v = idx_v[wave * neg + j];
        float2 ev = ((const float2*)(Wsnap + (size_t)v * D))[lane];
        float dot = wave_allreduce(eu.x * ev.x + eu.y * ev.y);
        float s = -fast_sig_lut(dot - NCE_NEG_BIAS, lut) * LR;
        dux += s * ev.x;
        duy += s * ev.y;
        float* wv = W + (size_t)v * D;
        atomicAdd(&wv[2 * lane],     s * eu.x);
        atomicAdd(&wv[2 * lane + 1], s * eu.y);
    }
    float* wu = W + (size_t)u * D;
    atomicAdd(&wu[2 * lane],     dux);
    atomicAdd(&wu[2 * lane + 1], duy);
}

extern "C" void kernel_launch(void* const* d_in, const int* in_sizes, int n_in,
                              void* d_out, int out_size, void* d_ws, size_t ws_size,
                              hipStream_t stream) {
    const float* W   = (const float*)d_in[0];
    const float* lut = (const float*)d_in[1];
    const int* ipu   = (const int*)d_in[2];
    const int* ipv   = (const int*)d_in[3];
    const int* inu   = (const int*)d_in[4];
    const int* inv   = (const int*)d_in[5];
    float* out = (float*)d_out;

    const int N  = in_sizes[0] / D;        // nodes
    const int Np = in_sizes[2];            // positive pairs
    const int Nn = in_sizes[4];            // negative pairs (N*NEG)
    const int NEG = Nn / Np;
    const size_t WB = (size_t)N * D * sizeof(float);
    const int nb = (N + 255) / 256;
    const int n_entp = 2 * Np;
    const int n_entn = NEG * Np + Nn;

    size_t need = (size_t)N * D * 2 * 2                       // w16W + w16P
                + (size_t)n_entp * 4 + (size_t)n_entn * 4
                + (size_t)N * 8 * 2 + (size_t)N * 4 * 2       // cnt2, cur2, off_p, off_n
                + (size_t)nb * 4 * 2 + 64;

    if (ws_size >= need) {
        char* p = (char*)d_ws;
        unsigned short* w16W = (unsigned short*)p; p += (size_t)N * D * 2;
        unsigned short* w16P = (unsigned short*)p; p += (size_t)N * D * 2;
        int*  ent_p = (int*)p;  p += (size_t)n_entp * 4;
        int*  ent_n = (int*)p;  p += (size_t)n_entn * 4;
        int2* cnt2  = (int2*)p; p += (size_t)N * 8;
        int2* cur2  = (int2*)p; p += (size_t)N * 8;
        int*  off_p = (int*)p;  p += (size_t)N * 4;
        int*  off_n = (int*)p;  p += (size_t)N * 4;
        int*  bsp   = (int*)p;  p += (size_t)nb * 4;
        int*  bsn   = (int*)p;

        hipMemsetAsync(cnt2, 0, (size_t)N * 8, stream);
        int n32 = N * 32;
        conv_kernel<<<(n32 + 255) / 256, 256, 0, stream>>>(W, w16W, n32);
        int tot = Np + Nn;
        hist_kernel<<<(tot + 255) / 256, 256, 0, stream>>>(ipu, ipv, inv, Np, Nn, NEG, cnt2);
        scan_local2<<<nb, 256, 0, stream>>>(cnt2, off_p, off_n, bsp, bsn, N);
        scan_bsum2<<<1, 256, 0, stream>>>(bsp, bsn, nb);
        add_base2<<<nb, 256, 0, stream>>>(off_p, off_n, cur2, bsp, bsn, N);
        fill_kernel<<<(tot + 255) / 256, 256, 0, stream>>>(ipu, ipv, inu, inv, Np, Nn, NEG,
                                                           cur2, ent_p, ent_n);

        int ublocks = (n32 + 255) / 256;
        // pos: base=W fp32, partners=bf16(W); write Wpos fp32 -> d_out + bf16 shadow -> w16P
        update_kernel<true><<<ublocks, 256, 0, stream>>>(
            W, w16W, out, w16P, off_p, (const int*)cur2, 0, ent_p, N, NCE_BIAS, 1.0f);
        // neg: base=own fp32 row of d_out (Wpos), partners=bf16(Wpos); overwrite own row
        update_kernel<false><<<ublocks, 256, 0, stream>>>(
            out, w16P, out, (unsigned short*)nullptr, off_n, (const int*)cur2, 1, ent_n,
            N, NCE_NEG_BIAS, 0.0f);
    } else {
        // scatter fallback (needs only one W-sized snapshot)
        float* snap = (float*)d_ws;
        hipMemcpyAsync(out, W, WB, hipMemcpyDeviceToDevice, stream);
        int blocks = (Np * 64 + 255) / 256;
        pos_kernel<<<blocks, 256, 0, stream>>>(W, out, lut, ipu, ipv, Np);
        hipMemcpyAsync(snap, out, WB, hipMemcpyDeviceToDevice, stream);
        neg_kernel<<<blocks, 256, 0, stream>>>(snap, out, lut, inu, inv, Np, NEG);
    }
}

// Round 2
// 271.375 us; speedup vs baseline: 1.0118x; 1.0047x over previous
//
#include <hip/hip_runtime.h>
#include <hip/hip_bf16.h>

#define D 128
#define LR 0.025f
#define NCE_BIAS 11.512925464970229f      // log(100000)
#define NCE_NEG_BIAS 9.903487552536127f   // log(100000/5)
#define LUT_SIZE 1202

__device__ __forceinline__ float wave_allreduce(float x) {
    #pragma unroll
    for (int m = 32; m >= 1; m >>= 1) x += __shfl_xor(x, m, 64);
    return x;
}

// Analytic stand-in for the reference's LUT sigmoid (centered quantization err <=1.25e-3).
__device__ __forceinline__ float fast_sig(float x) {
    x = fminf(fmaxf(x, -6.0f), 6.0f) - 0.005f;
    float e = __expf(-x);
    return __builtin_amdgcn_rcpf(1.0f + e);
}

__device__ __forceinline__ float fast_sig_lut(float s, const float* __restrict__ lut) {
    s = fminf(fmaxf(s, -6.0f), 6.0f);
    int idx = (int)floorf((s + 6.01f) / 0.01f);
    idx = min(max(idx, 0), LUT_SIZE - 1);
    return lut[idx];
}

__device__ __forceinline__ unsigned int bf16_rne(float f) {
    unsigned int u = __float_as_uint(f);
    return (u + 0x7FFFu + ((u >> 16) & 1u)) >> 16;
}

// ---------------- fused W->bf16 shadow + degree histogram ----------------
// Blocks [0, cb): conv (bf16 shadow). Blocks [cb, cb+hb): histogram.
// Independent outputs; memset(cnt2) is a prior graph node.
__global__ __launch_bounds__(256) void convhist_kernel(
    const float* __restrict__ W, unsigned short* __restrict__ w16, int n32, int cb,
    const int* __restrict__ ipu, const int* __restrict__ ipv,
    const int* __restrict__ inv,
    int Np, int Nn, int NEG, int2* __restrict__ cnt2)
{
    int b = blockIdx.x;
    if (b < cb) {
        int g = b * 256 + threadIdx.x;
        if (g >= n32) return;
        float4 v = ((const float4*)W)[g];
        uint2 h;
        h.x = bf16_rne(v.x) | (bf16_rne(v.y) << 16);
        h.y = bf16_rne(v.z) | (bf16_rne(v.w) << 16);
        ((uint2*)w16)[g] = h;
    } else {
        int t = (b - cb) * 256 + threadIdx.x;
        if (t < Np) {
            atomicAdd((unsigned long long*)&cnt2[ipu[t]],
                      1ull + ((unsigned long long)NEG << 32));
            atomicAdd(&cnt2[ipv[t]].x, 1);
        } else if (t < Np + Nn) {
            int k = t - Np;
            atomicAdd(&cnt2[inv[k]].y, 1);
        }
    }
}

// ---------------- single-pass dual exclusive scan (decoupled lookback) ----
// Replaces scan_local2 + scan_bsum2 + add_base2 (3 dispatches -> 1).
// Ticketed: a block holding ticket t implies tickets 0..t-1 are already
// executing => their aggregates WILL be published => spin is deadlock-free
// regardless of residency. Publication is a single 64-bit atomicExch of
// {posAgg+1 (lo32), negAgg (hi32)}; lo32 != 0 doubles as the ready flag, so
// no separate fence/flag ordering is needed. ticket + partials are zeroed by
// the same memset node that zeroes cnt2 (graph replay safe).
__global__ __launch_bounds__(256) void scan_fused(
    const int2* __restrict__ cnt2,
    int* __restrict__ off_p, int* __restrict__ off_n, int2* __restrict__ cur2,
    unsigned long long* __restrict__ partials, int* __restrict__ ticket, int n)
{
    __shared__ int shp[256], shn[256];
    __shared__ int tkt_s;
    if (threadIdx.x == 0) tkt_s = atomicAdd(ticket, 1);
    __syncthreads();
    const int t = tkt_s;

    int g = t * 256 + threadIdx.x;
    int2 x = (g < n) ? cnt2[g] : make_int2(0, 0);
    shp[threadIdx.x] = x.x;
    shn[threadIdx.x] = x.y;
    __syncthreads();
    #pragma unroll
    for (int d = 1; d < 256; d <<= 1) {
        int tp = (threadIdx.x >= d) ? shp[threadIdx.x - d] : 0;
        int tn = (threadIdx.x >= d) ? shn[threadIdx.x - d] : 0;
        __syncthreads();
        shp[threadIdx.x] += tp;
        shn[threadIdx.x] += tn;
        __syncthreads();
    }
    int incP = shp[threadIdx.x];          // inclusive local scan
    int incN = shn[threadIdx.x];

    if (threadIdx.x == 255) {
        unsigned long long v = (unsigned long long)(unsigned int)(incP + 1)
                             | ((unsigned long long)(unsigned int)incN << 32);
        atomicExch(&partials[t], v);      // atomic 64-bit publish (agg+flag in one word)
    }

    // lookback: sum aggregates of all predecessor tickets
    int myP = 0, myN = 0;
    for (int i = threadIdx.x; i < t; i += 256) {
        unsigned long long v;
        do {
            v = atomicAdd(&partials[i], 0ull);     // device-scope atomic read
        } while ((v & 0xFFFFFFFFull) == 0ull);
        myP += (int)(v & 0xFFFFFFFFull) - 1;
        myN += (int)(v >> 32);
    }
    __syncthreads();                       // shp/shn free for reuse
    shp[threadIdx.x] = myP;
    shn[threadIdx.x] = myN;
    __syncthreads();
    #pragma unroll
    for (int d = 128; d > 0; d >>= 1) {
        if (threadIdx.x < d) {
            shp[threadIdx.x] += shp[threadIdx.x + d];
            shn[threadIdx.x] += shn[threadIdx.x + d];
        }
        __syncthreads();
    }
    const int baseP = shp[0];
    const int baseN = shn[0];

    if (g < n) {
        int vp = incP - x.x + baseP;       // exclusive + global base
        int vn = incN - x.y + baseN;
        off_p[g] = vp;
        off_n[g] = vn;
        cur2[g] = make_int2(vp, vn);
    }
}

// pos pair t: ONE 64-bit atomic reserves the u-side pos slot AND NEG contiguous
// neg slots; neg partners written contiguously.
__global__ __launch_bounds__(256) void fill_kernel(
    const int* __restrict__ ipu, const int* __restrict__ ipv,
    const int* __restrict__ inu, const int* __restrict__ inv,
    int Np, int Nn, int NEG,
    int2* __restrict__ cur2, int* __restrict__ ent_p, int* __restrict__ ent_n)
{
    int t = blockIdx.x * 256 + threadIdx.x;
    if (t < Np) {
        int u = ipu[t], v = ipv[t];
        unsigned long long pk = atomicAdd((unsigned long long*)&cur2[u],
                                          1ull + ((unsigned long long)NEG << 32));
        int slot_pu = (int)(pk & 0xFFFFFFFFull);
        int slot_nu = (int)(pk >> 32);
        ent_p[slot_pu] = v;
        for (int j = 0; j < NEG; ++j)
            ent_n[slot_nu + j] = inv[(size_t)NEG * t + j];
        ent_p[atomicAdd(&cur2[v].x, 1)] = u;
    } else if (t < Np + Nn) {
        int k = t - Np;
        ent_n[atomicAdd(&cur2[inv[k]].y, 1)] = inu[k];
    }
}

// ---------------- pull update (software-pipelined) ----------------
// Half-wave per node (32 lanes x float4 base). Partners are bf16 (256B rows).
// Entries prefetched 2 groups ahead; partner rows 1 group ahead (8 loads in flight).
// Select-exchange multi-reduce: 6 shfl + 6 add + 6 sel replaces 20 shfl + 20
// add; score computed once per lane (lane class b4,b3 owns entry 2*b4+b3),
// then 3 shfl + 8 sel broadcast the 4 scores. Bit-identical xor tree.
template<bool EMIT16>
__global__ __launch_bounds__(256) void update_kernel(
    const float* __restrict__ baseSrc,
    const unsigned short* __restrict__ partnerH,
    float* __restrict__ dst, unsigned short* __restrict__ dst16,
    const int* __restrict__ offArr, const int* __restrict__ endArr2, int comp,
    const int* __restrict__ entries, int N, float bias, float cpos)
{
    int gtid = blockIdx.x * 256 + threadIdx.x;
    int node = gtid >> 5;
    int hl   = threadIdx.x & 31;
    if (node >= N) return;

    const bool b3 = (hl & 8) != 0;
    const bool b4 = (hl & 16) != 0;
    const int i_lane = (hl >> 3) & 3;   // which entry's dot this lane owns post-reduce

    float4 base = ((const float4*)baseSrc)[(size_t)node * 32 + hl];
    float ax = 0.0f, ay = 0.0f, az = 0.0f, aw = 0.0f;

    int beg = offArr[node];
    int len = endArr2[2 * node + comp] - beg;
    const uint2* ph = (const uint2*)partnerH;

    if (len > 0) {
        int gcount = (len + 3) >> 2;
        int en[4];
        uint2 rc[4];
        #pragma unroll
        for (int i = 0; i < 4; ++i) {
            int t = min(i, len - 1);
            rc[i] = ph[(size_t)entries[beg + t] * 32 + hl];
        }
        #pragma unroll
        for (int i = 0; i < 4; ++i) {
            int t = min(4 + i, len - 1);
            en[i] = entries[beg + t];
        }
        for (int g = 0; g < gcount; ++g) {
            uint2 rn[4];
            #pragma unroll
            for (int i = 0; i < 4; ++i) rn[i] = ph[(size_t)en[i] * 32 + hl];
            int en2[4];
            #pragma unroll
            for (int i = 0; i < 4; ++i) {
                int t = (g + 2) * 4 + i;
                t = (t < len) ? t : (len - 1);
                en2[i] = entries[beg + t];
            }
            float4 r[4];
            float d[4];
            #pragma unroll
            for (int i = 0; i < 4; ++i) {
                r[i].x = __uint_as_float(rc[i].x << 16);
                r[i].y = __uint_as_float(rc[i].x & 0xFFFF0000u);
                r[i].z = __uint_as_float(rc[i].y << 16);
                r[i].w = __uint_as_float(rc[i].y & 0xFFFF0000u);
                d[i] = r[i].x * base.x + r[i].y * base.y + r[i].z * base.z + r[i].w * base.w;
            }
            // ---- select-exchange multi-reduce (same xor tree as before) ----
            float y0 = b4 ? d[0] : d[2];
            float y1 = b4 ? d[1] : d[3];
            y0 = __shfl_xor(y0, 16, 64);
            y1 = __shfl_xor(y1, 16, 64);
            float pa = b4 ? (d[2] + y0) : (d[0] + y0);
            float pb = b4 ? (d[3] + y1) : (d[1] + y1);
            float y2 = b3 ? pa : pb;
            y2 = __shfl_xor(y2, 8, 64);
            float cc = b3 ? (pb + y2) : (pa + y2);
            cc += __shfl_xor(cc, 4, 64);
            cc += __shfl_xor(cc, 2, 64);
            cc += __shfl_xor(cc, 1, 64);

            // ---- one score per lane (was 4x per lane) ----
            float s = (g * 4 + i_lane < len)
                        ? (cpos - fast_sig(cc - bias)) * LR : 0.0f;

            // ---- broadcast 4 scores to all lanes ----
            float t8  = __shfl_xor(s, 8, 64);
            float t16 = __shfl_xor(s, 16, 64);
            float t24 = __shfl_xor(t8, 16, 64);
            float p  = b3 ? t8  : s;
            float q  = b3 ? s   : t8;
            float p2 = b3 ? t24 : t16;
            float q2 = b3 ? t16 : t24;
            float se[4];
            se[0] = b4 ? p2 : p;
            se[1] = b4 ? q2 : q;
            se[2] = b4 ? p  : p2;
            se[3] = b4 ? q  : q2;

            #pragma unroll
            for (int i = 0; i < 4; ++i) {
                ax += se[i] * r[i].x;
                ay += se[i] * r[i].y;
                az += se[i] * r[i].z;
                aw += se[i] * r[i].w;
            }
            #pragma unroll
            for (int i = 0; i < 4; ++i) { rc[i] = rn[i]; en[i] = en2[i]; }
        }
    }
    float4 o = make_float4(base.x + ax, base.y + ay, base.z + az, base.w + aw);
    ((float4*)dst)[(size_t)node * 32 + hl] = o;
    if (EMIT16) {
        uint2 h;
        h.x = bf16_rne(o.x) | (bf16_rne(o.y) << 16);
        h.y = bf16_rne(o.z) | (bf16_rne(o.w) << 16);
        ((uint2*)dst16)[(size_t)node * 32 + hl] = h;
    }
}

// ---------------- fallback scatter path (round-1, known-good) ----------------
__global__ __launch_bounds__(256) void pos_kernel(
    const float* __restrict__ Worig, float* __restrict__ W,
    const float* __restrict__ lut,
    const int* __restrict__ idx_u, const int* __restrict__ idx_v, int n)
{
    int wave = (int)((blockIdx.x * blockDim.x + threadIdx.x) >> 6);
    int lane = threadIdx.x & 63;
    if (wave >= n) return;
    int u = idx_u[wave];
    int v = idx_v[wave];
    float2 eu = ((const float2*)(Worig + (size_t)u * D))[lane];
    float2 ev = ((const float2*)(Worig + (size_t)v * D))[lane];
    float dot = wave_allreduce(eu.x * ev.x + eu.y * ev.y);
    float s = (1.0f - fast_sig_lut(dot - NCE_BIAS, lut)) * LR;
    float* wu = W + (size_t)u * D;
    float* wv = W + (size_t)v * D;
    atomicAdd(&wu[2 * lane],     s * ev.x);
    atomicAdd(&wu[2 * lane + 1], s * ev.y);
    atomicAdd(&wv[2 * lane],     s * eu.x);
    atomicAdd(&wv[2 * lane + 1], s * eu.y);
}

__global__ __launch_bounds__(256) void neg_kernel(
    const float* __restrict__ Wsnap, float* __restrict__ W,
    const float* __restrict__ lut,
    const int* __restrict__ idx_u, const int* __restrict__ idx_v, int n, int neg)
{
    int wave = (int)((blockIdx.x * blockDim.x + threadIdx.x) >> 6);
    int lane = threadIdx.x & 63;
    if (wave >= n) return;
    int u = idx_u[wave * neg];
    float2 eu = ((const float2*)(Wsnap + (size_t)u * D))[lane];
    float dux = 0.0f, duy = 0.0f;
    for (int j = 0; j < neg; ++j) {
        int v = idx_v[wave * neg + j];
        float2 ev = ((const float2*)(Wsnap + (size_t)v * D))[lane];
        float dot = wave_allreduce(eu.x * ev.x + eu.y * ev.y);
        float s = -fast_sig_lut(dot - NCE_NEG_BIAS, lut) * LR;
        dux += s * ev.x;
        duy += s * ev.y;
        float* wv = W + (size_t)v * D;
        atomicAdd(&wv[2 * lane],     s * eu.x);
        atomicAdd(&wv[2 * lane + 1], s * eu.y);
    }
    float* wu = W + (size_t)u * D;
    atomicAdd(&wu[2 * lane],     dux);
    atomicAdd(&wu[2 * lane + 1], duy);
}

extern "C" void kernel_launch(void* const* d_in, const int* in_sizes, int n_in,
                              void* d_out, int out_size, void* d_ws, size_t ws_size,
                              hipStream_t stream) {
    const float* W   = (const float*)d_in[0];
    const float* lut = (const float*)d_in[1];
    const int* ipu   = (const int*)d_in[2];
    const int* ipv   = (const int*)d_in[3];
    const int* inu   = (const int*)d_in[4];
    const int* inv   = (const int*)d_in[5];
    float* out = (float*)d_out;

    const int N  = in_sizes[0] / D;        // nodes
    const int Np = in_sizes[2];            // positive pairs
    const int Nn = in_sizes[4];            // negative pairs (N*NEG)
    const int NEG = Nn / Np;
    const size_t WB = (size_t)N * D * sizeof(float);
    const int nb = (N + 255) / 256;
    const int n_entp = 2 * Np;
    const int n_entn = NEG * Np + Nn;

    size_t need = (size_t)N * D * 2 * 2                       // w16W + w16P
                + (size_t)n_entp * 4 + (size_t)n_entn * 4
                + (size_t)N * 8                               // cnt2
                + 16 + (size_t)nb * 8                          // ticket + partials
                + (size_t)N * 8 + (size_t)N * 4 * 2           // cur2, off_p, off_n
                + 64;

    if (ws_size >= need) {
        char* p = (char*)d_ws;
        unsigned short* w16W = (unsigned short*)p; p += (size_t)N * D * 2;
        unsigned short* w16P = (unsigned short*)p; p += (size_t)N * D * 2;
        int*  ent_p = (int*)p;  p += (size_t)n_entp * 4;
        int*  ent_n = (int*)p;  p += (size_t)n_entn * 4;
        // --- contiguous zeroed region: cnt2 | ticket | partials ---
        char* zbase = p;
        int2* cnt2  = (int2*)p; p += (size_t)N * 8;
        int*  ticket = (int*)p; p += 16;
        unsigned long long* partials = (unsigned long long*)p; p += (size_t)nb * 8;
        size_t zbytes = (size_t)(p - zbase);
        int2* cur2  = (int2*)p; p += (size_t)N * 8;
        int*  off_p = (int*)p;  p += (size_t)N * 4;
        int*  off_n = (int*)p;

        hipMemsetAsync(zbase, 0, zbytes, stream);
        int n32 = N * 32;
        int cb = (n32 + 255) / 256;
        int hb = (Np + Nn + 255) / 256;
        convhist_kernel<<<cb + hb, 256, 0, stream>>>(W, w16W, n32, cb,
                                                     ipu, ipv, inv, Np, Nn, NEG, cnt2);
        scan_fused<<<nb, 256, 0, stream>>>(cnt2, off_p, off_n, cur2, partials, ticket, N);
        int tot = Np + Nn;
        fill_kernel<<<(tot + 255) / 256, 256, 0, stream>>>(ipu, ipv, inu, inv, Np, Nn, NEG,
                                                           cur2, ent_p, ent_n);

        int ublocks = (n32 + 255) / 256;
        // pos: base=W fp32, partners=bf16(W); write Wpos fp32 -> d_out + bf16 shadow -> w16P
        update_kernel<true><<<ublocks, 256, 0, stream>>>(
            W, w16W, out, w16P, off_p, (const int*)cur2, 0, ent_p, N, NCE_BIAS, 1.0f);
        // neg: base=own fp32 row of d_out (Wpos), partners=bf16(Wpos); overwrite own row
        update_kernel<false><<<ublocks, 256, 0, stream>>>(
            out, w16P, out, (unsigned short*)nullptr, off_n, (const int*)cur2, 1, ent_n,
            N, NCE_NEG_BIAS, 0.0f);
    } else {
        // scatter fallback (needs only one W-sized snapshot)
        float* snap = (float*)d_ws;
        hipMemcpyAsync(out, W, WB, hipMemcpyDeviceToDevice, stream);
        int blocks = (Np * 64 + 255) / 256;
        pos_kernel<<<blocks, 256, 0, stream>>>(W, out, lut, ipu, ipv, Np);
        hipMemcpyAsync(snap, out, WB, hipMemcpyDeviceToDevice, stream);
        neg_kernel<<<blocks, 256, 0, stream>>>(snap, out, lut, inu, inv, Np, NEG);
    }
}

// Round 3
// 270.161 us; speedup vs baseline: 1.0163x; 1.0045x over previous
//
#include <hip/hip_runtime.h>
#include <hip/hip_bf16.h>

#define D 128
#define LR 0.025f
#define NCE_BIAS 11.512925464970229f      // log(100000)
#define NCE_NEG_BIAS 9.903487552536127f   // log(100000/5)
#define LUT_SIZE 1202

__device__ __forceinline__ float wave_allreduce(float x) {
    #pragma unroll
    for (int m = 32; m >= 1; m >>= 1) x += __shfl_xor(x, m, 64);
    return x;
}

// Analytic stand-in for the reference's LUT sigmoid (centered quantization err <=1.25e-3).
__device__ __forceinline__ float fast_sig(float x) {
    x = fminf(fmaxf(x, -6.0f), 6.0f) - 0.005f;
    float e = __expf(-x);
    return __builtin_amdgcn_rcpf(1.0f + e);
}

__device__ __forceinline__ float fast_sig_lut(float s, const float* __restrict__ lut) {
    s = fminf(fmaxf(s, -6.0f), 6.0f);
    int idx = (int)floorf((s + 6.01f) / 0.01f);
    idx = min(max(idx, 0), LUT_SIZE - 1);
    return lut[idx];
}

__device__ __forceinline__ unsigned int bf16_rne(float f) {
    unsigned int u = __float_as_uint(f);
    return (u + 0x7FFFu + ((u >> 16) & 1u)) >> 16;
}

// ---------------- fused W->bf16 shadow + degree histogram ----------------
// Blocks [0, cb): conv (bf16 shadow). Blocks [cb, cb+hb): histogram.
// Independent outputs; memset(cnt2) is a prior graph node.
__global__ __launch_bounds__(256) void convhist_kernel(
    const float* __restrict__ W, unsigned short* __restrict__ w16, int n32, int cb,
    const int* __restrict__ ipu, const int* __restrict__ ipv,
    const int* __restrict__ inv,
    int Np, int Nn, int NEG, int2* __restrict__ cnt2)
{
    int b = blockIdx.x;
    if (b < cb) {
        int g = b * 256 + threadIdx.x;
        if (g >= n32) return;
        float4 v = ((const float4*)W)[g];
        uint2 h;
        h.x = bf16_rne(v.x) | (bf16_rne(v.y) << 16);
        h.y = bf16_rne(v.z) | (bf16_rne(v.w) << 16);
        ((uint2*)w16)[g] = h;
    } else {
        int t = (b - cb) * 256 + threadIdx.x;
        if (t < Np) {
            atomicAdd((unsigned long long*)&cnt2[ipu[t]],
                      1ull + ((unsigned long long)NEG << 32));
            atomicAdd(&cnt2[ipv[t]].x, 1);
        } else if (t < Np + Nn) {
            int k = t - Np;
            atomicAdd(&cnt2[inv[k]].y, 1);
        }
    }
}

// ---------------- single-pass dual exclusive scan (decoupled lookback) ----
// Ticketed: a block holding ticket t implies tickets 0..t-1 are already
// executing => their aggregates WILL be published => spin is deadlock-free.
// Publication is a single 64-bit atomicExch of {posAgg+1 (lo32), negAgg
// (hi32)}; lo32 != 0 doubles as the ready flag. ticket + partials are zeroed
// by the same memset node that zeroes cnt2 (graph replay safe).
__global__ __launch_bounds__(256) void scan_fused(
    const int2* __restrict__ cnt2,
    int* __restrict__ off_p, int* __restrict__ off_n, int2* __restrict__ cur2,
    unsigned long long* __restrict__ partials, int* __restrict__ ticket, int n)
{
    __shared__ int shp[256], shn[256];
    __shared__ int tkt_s;
    if (threadIdx.x == 0) tkt_s = atomicAdd(ticket, 1);
    __syncthreads();
    const int t = tkt_s;

    int g = t * 256 + threadIdx.x;
    int2 x = (g < n) ? cnt2[g] : make_int2(0, 0);
    shp[threadIdx.x] = x.x;
    shn[threadIdx.x] = x.y;
    __syncthreads();
    #pragma unroll
    for (int d = 1; d < 256; d <<= 1) {
        int tp = (threadIdx.x >= d) ? shp[threadIdx.x - d] : 0;
        int tn = (threadIdx.x >= d) ? shn[threadIdx.x - d] : 0;
        __syncthreads();
        shp[threadIdx.x] += tp;
        shn[threadIdx.x] += tn;
        __syncthreads();
    }
    int incP = shp[threadIdx.x];          // inclusive local scan
    int incN = shn[threadIdx.x];

    if (threadIdx.x == 255) {
        unsigned long long v = (unsigned long long)(unsigned int)(incP + 1)
                             | ((unsigned long long)(unsigned int)incN << 32);
        atomicExch(&partials[t], v);      // atomic 64-bit publish (agg+flag in one word)
    }

    // lookback: sum aggregates of all predecessor tickets
    int myP = 0, myN = 0;
    for (int i = threadIdx.x; i < t; i += 256) {
        unsigned long long v;
        do {
            v = atomicAdd(&partials[i], 0ull);     // device-scope atomic read
        } while ((v & 0xFFFFFFFFull) == 0ull);
        myP += (int)(v & 0xFFFFFFFFull) - 1;
        myN += (int)(v >> 32);
    }
    __syncthreads();                       // shp/shn free for reuse
    shp[threadIdx.x] = myP;
    shn[threadIdx.x] = myN;
    __syncthreads();
    #pragma unroll
    for (int d = 128; d > 0; d >>= 1) {
        if (threadIdx.x < d) {
            shp[threadIdx.x] += shp[threadIdx.x + d];
            shn[threadIdx.x] += shn[threadIdx.x + d];
        }
        __syncthreads();
    }
    const int baseP = shp[0];
    const int baseN = shn[0];

    if (g < n) {
        int vp = incP - x.x + baseP;       // exclusive + global base
        int vn = incN - x.y + baseN;
        off_p[g] = vp;
        off_n[g] = vn;
        cur2[g] = make_int2(vp, vn);
    }
}

// pos pair t: ONE 64-bit atomic reserves the u-side pos slot AND NEG contiguous
// neg slots; neg partners written contiguously.
__global__ __launch_bounds__(256) void fill_kernel(
    const int* __restrict__ ipu, const int* __restrict__ ipv,
    const int* __restrict__ inu, const int* __restrict__ inv,
    int Np, int Nn, int NEG,
    int2* __restrict__ cur2, int* __restrict__ ent_p, int* __restrict__ ent_n)
{
    int t = blockIdx.x * 256 + threadIdx.x;
    if (t < Np) {
        int u = ipu[t], v = ipv[t];
        unsigned long long pk = atomicAdd((unsigned long long*)&cur2[u],
                                          1ull + ((unsigned long long)NEG << 32));
        int slot_pu = (int)(pk & 0xFFFFFFFFull);
        int slot_nu = (int)(pk >> 32);
        ent_p[slot_pu] = v;
        for (int j = 0; j < NEG; ++j)
            ent_n[slot_nu + j] = inv[(size_t)NEG * t + j];
        ent_p[atomicAdd(&cur2[v].x, 1)] = u;
    } else if (t < Np + Nn) {
        int k = t - Np;
        ent_n[atomicAdd(&cur2[inv[k]].y, 1)] = inu[k];
    }
}

// ---------------- pull update (software-pipelined) ----------------
// Half-wave per node (32 lanes x float4 base). Partners are bf16 (256B rows).
// Entries prefetched 2 groups ahead; partner rows 1 group ahead.
// This round:
//  - UNCLAMPED prefetch: ent arrays are followed by valid ints (next list /
//    64B zero pad after ent_n), so overrun reads are valid node ids whose
//    contribution is already masked to score=0. Removes all min/cmp/csel
//    index math from the pipeline.
//  - 32-bit partner addressing: byte offset = (entry<<8) + (hl<<3) off a
//    uniform base (tables < 4 GiB) instead of 64-bit mul chains.
//  - #pragma unroll 2 on the g-loop so the rc=rn/en=en2 pipeline rotation
//    becomes register ping-pong (kills 12 v_mov per group).
// Select-exchange multi-reduce unchanged (bit-identical xor tree).
template<bool EMIT16>
__global__ __launch_bounds__(256) void update_kernel(
    const float* __restrict__ baseSrc,
    const unsigned short* __restrict__ partnerH,
    float* __restrict__ dst, unsigned short* __restrict__ dst16,
    const int* __restrict__ offArr, const int* __restrict__ endArr2, int comp,
    const int* __restrict__ entries, int N, float bias, float cpos)
{
    int gtid = blockIdx.x * 256 + threadIdx.x;
    int node = gtid >> 5;
    int hl   = threadIdx.x & 31;
    if (node >= N) return;

    const bool b3 = (hl & 8) != 0;
    const bool b4 = (hl & 16) != 0;
    const int i_lane = (hl >> 3) & 3;   // which entry's dot this lane owns post-reduce
    const char* __restrict__ phb = (const char*)partnerH;
    const unsigned loff = (unsigned)hl << 3;   // lane byte offset within 256B row

    float4 base = ((const float4*)baseSrc)[(size_t)node * 32 + hl];
    float ax = 0.0f, ay = 0.0f, az = 0.0f, aw = 0.0f;

    int beg = offArr[node];
    int len = endArr2[2 * node + comp] - beg;
    const int* __restrict__ ep = entries + beg;  // may read up to ep[len+10]: padded

    if (len > 0) {
        int gcount = (len + 3) >> 2;
        int en[4];
        uint2 rc[4];
        #pragma unroll
        for (int i = 0; i < 4; ++i)
            rc[i] = *(const uint2*)(phb + ((unsigned)ep[i] << 8) + loff);
        #pragma unroll
        for (int i = 0; i < 4; ++i) en[i] = ep[4 + i];

        #pragma unroll 2
        for (int g = 0; g < gcount; ++g) {
            uint2 rn[4];
            #pragma unroll
            for (int i = 0; i < 4; ++i)
                rn[i] = *(const uint2*)(phb + ((unsigned)en[i] << 8) + loff);
            int en2[4];
            #pragma unroll
            for (int i = 0; i < 4; ++i) en2[i] = ep[(g + 2) * 4 + i];

            float4 r[4];
            float d[4];
            #pragma unroll
            for (int i = 0; i < 4; ++i) {
                r[i].x = __uint_as_float(rc[i].x << 16);
                r[i].y = __uint_as_float(rc[i].x & 0xFFFF0000u);
                r[i].z = __uint_as_float(rc[i].y << 16);
                r[i].w = __uint_as_float(rc[i].y & 0xFFFF0000u);
                d[i] = r[i].x * base.x + r[i].y * base.y + r[i].z * base.z + r[i].w * base.w;
            }
            // ---- select-exchange multi-reduce (same xor tree as before) ----
            float y0 = b4 ? d[0] : d[2];
            float y1 = b4 ? d[1] : d[3];
            y0 = __shfl_xor(y0, 16, 64);
            y1 = __shfl_xor(y1, 16, 64);
            float pa = (b4 ? d[2] : d[0]) + y0;
            float pb = (b4 ? d[3] : d[1]) + y1;
            float y2 = b3 ? pa : pb;
            y2 = __shfl_xor(y2, 8, 64);
            float cc = (b3 ? pb : pa) + y2;
            cc += __shfl_xor(cc, 4, 64);
            cc += __shfl_xor(cc, 2, 64);
            cc += __shfl_xor(cc, 1, 64);

            // ---- one score per lane (lane class b4,b3 owns entry 2*b4+b3) ----
            float s = (g * 4 + i_lane < len)
                        ? (cpos - fast_sig(cc - bias)) * LR : 0.0f;

            // ---- broadcast 4 scores to all lanes ----
            float t8  = __shfl_xor(s, 8, 64);
            float t16 = __shfl_xor(s, 16, 64);
            float t24 = __shfl_xor(t8, 16, 64);
            float p  = b3 ? t8  : s;
            float q  = b3 ? s   : t8;
            float p2 = b3 ? t24 : t16;
            float q2 = b3 ? t16 : t24;
            float se[4];
            se[0] = b4 ? p2 : p;
            se[1] = b4 ? q2 : q;
            se[2] = b4 ? p  : p2;
            se[3] = b4 ? q  : q2;

            #pragma unroll
            for (int i = 0; i < 4; ++i) {
                ax += se[i] * r[i].x;
                ay += se[i] * r[i].y;
                az += se[i] * r[i].z;
                aw += se[i] * r[i].w;
            }
            #pragma unroll
            for (int i = 0; i < 4; ++i) { rc[i] = rn[i]; en[i] = en2[i]; }
        }
    }
    float4 o = make_float4(base.x + ax, base.y + ay, base.z + az, base.w + aw);
    ((float4*)dst)[(size_t)node * 32 + hl] = o;
    if (EMIT16) {
        uint2 h;
        h.x = bf16_rne(o.x) | (bf16_rne(o.y) << 16);
        h.y = bf16_rne(o.z) | (bf16_rne(o.w) << 16);
        ((uint2*)dst16)[(size_t)node * 32 + hl] = h;
    }
}

// ---------------- fallback scatter path (round-1, known-good) ----------------
__global__ __launch_bounds__(256) void pos_kernel(
    const float* __restrict__ Worig, float* __restrict__ W,
    const float* __restrict__ lut,
    const int* __restrict__ idx_u, const int* __restrict__ idx_v, int n)
{
    int wave = (int)((blockIdx.x * blockDim.x + threadIdx.x) >> 6);
    int lane = threadIdx.x & 63;
    if (wave >= n) return;
    int u = idx_u[wave];
    int v = idx_v[wave];
    float2 eu = ((const float2*)(Worig + (size_t)u * D))[lane];
    float2 ev = ((const float2*)(Worig + (size_t)v * D))[lane];
    float dot = wave_allreduce(eu.x * ev.x + eu.y * ev.y);
    float s = (1.0f - fast_sig_lut(dot - NCE_BIAS, lut)) * LR;
    float* wu = W + (size_t)u * D;
    float* wv = W + (size_t)v * D;
    atomicAdd(&wu[2 * lane],     s * ev.x);
    atomicAdd(&wu[2 * lane + 1], s * ev.y);
    atomicAdd(&wv[2 * lane],     s * eu.x);
    atomicAdd(&wv[2 * lane + 1], s * eu.y);
}

__global__ __launch_bounds__(256) void neg_kernel(
    const float* __restrict__ Wsnap, float* __restrict__ W,
    const float* __restrict__ lut,
    const int* __restrict__ idx_u, const int* __restrict__ idx_v, int n, int neg)
{
    int wave = (int)((blockIdx.x * blockDim.x + threadIdx.x) >> 6);
    int lane = threadIdx.x & 63;
    if (wave >= n) return;
    int u = idx_u[wave * neg];
    float2 eu = ((const float2*)(Wsnap + (size_t)u * D))[lane];
    float dux = 0.0f, duy = 0.0f;
    for (int j = 0; j < neg; ++j) {
        int v = idx_v[wave * neg + j];
        float2 ev = ((const float2*)(Wsnap + (size_t)v * D))[lane];
        float dot = wave_allreduce(eu.x * ev.x + eu.y * ev.y);
        float s = -fast_sig_lut(dot - NCE_NEG_BIAS, lut) * LR;
        dux += s * ev.x;
        duy += s * ev.y;
        float* wv = W + (size_t)v * D;
        atomicAdd(&wv[2 * lane],     s * eu.x);
        atomicAdd(&wv[2 * lane + 1], s * eu.y);
    }
    float* wu = W + (size_t)u * D;
    atomicAdd(&wu[2 * lane],     dux);
    atomicAdd(&wu[2 * lane + 1], duy);
}

extern "C" void kernel_launch(void* const* d_in, const int* in_sizes, int n_in,
                              void* d_out, int out_size, void* d_ws, size_t ws_size,
                              hipStream_t stream) {
    const float* W   = (const float*)d_in[0];
    const float* lut = (const float*)d_in[1];
    const int* ipu   = (const int*)d_in[2];
    const int* ipv   = (const int*)d_in[3];
    const int* inu   = (const int*)d_in[4];
    const int* inv   = (const int*)d_in[5];
    float* out = (float*)d_out;

    const int N  = in_sizes[0] / D;        // nodes
    const int Np = in_sizes[2];            // positive pairs
    const int Nn = in_sizes[4];            // negative pairs (N*NEG)
    const int NEG = Nn / Np;
    const size_t WB = (size_t)N * D * sizeof(float);
    const int nb = (N + 255) / 256;
    const int n_entp = 2 * Np;
    const int n_entn = NEG * Np + Nn;

    size_t need = (size_t)N * D * 2 * 2                       // w16W + w16P
                + (size_t)n_entp * 4 + (size_t)n_entn * 4
                + 64                                          // zero pad after ent_n
                + (size_t)N * 8                               // cnt2
                + 16 + (size_t)nb * 8                         // ticket + partials
                + (size_t)N * 8 + (size_t)N * 4 * 2           // cur2, off_p, off_n
                + 64;

    if (ws_size >= need) {
        char* p = (char*)d_ws;
        unsigned short* w16W = (unsigned short*)p; p += (size_t)N * D * 2;
        unsigned short* w16P = (unsigned short*)p; p += (size_t)N * D * 2;
        int*  ent_p = (int*)p;  p += (size_t)n_entp * 4;
        int*  ent_n = (int*)p;  p += (size_t)n_entn * 4;
        // --- contiguous zeroed region: entry-overrun pad | cnt2 | ticket | partials ---
        char* zbase = p;
        p += 64;                                  // 16 zero ints: ent_n overrun pad
        int2* cnt2  = (int2*)p; p += (size_t)N * 8;
        int*  ticket = (int*)p; p += 16;
        unsigned long long* partials = (unsigned long long*)p; p += (size_t)nb * 8;
        size_t zbytes = (size_t)(p - zbase);
        int2* cur2  = (int2*)p; p += (size_t)N * 8;
        int*  off_p = (int*)p;  p += (size_t)N * 4;
        int*  off_n = (int*)p;

        hipMemsetAsync(zbase, 0, zbytes, stream);
        int n32 = N * 32;
        int cb = (n32 + 255) / 256;
        int hb = (Np + Nn + 255) / 256;
        convhist_kernel<<<cb + hb, 256, 0, stream>>>(W, w16W, n32, cb,
                                                     ipu, ipv, inv, Np, Nn, NEG, cnt2);
        scan_fused<<<nb, 256, 0, stream>>>(cnt2, off_p, off_n, cur2, partials, ticket, N);
        int tot = Np + Nn;
        fill_kernel<<<(tot + 255) / 256, 256, 0, stream>>>(ipu, ipv, inu, inv, Np, Nn, NEG,
                                                           cur2, ent_p, ent_n);

        int ublocks = (n32 + 255) / 256;
        // pos: base=W fp32, partners=bf16(W); write Wpos fp32 -> d_out + bf16 shadow -> w16P
        update_kernel<true><<<ublocks, 256, 0, stream>>>(
            W, w16W, out, w16P, off_p, (const int*)cur2, 0, ent_p, N, NCE_BIAS, 1.0f);
        // neg: base=own fp32 row of d_out (Wpos), partners=bf16(Wpos); overwrite own row
        update_kernel<false><<<ublocks, 256, 0, stream>>>(
            out, w16P, out, (unsigned short*)nullptr, off_n, (const int*)cur2, 1, ent_n,
            N, NCE_NEG_BIAS, 0.0f);
    } else {
        // scatter fallback (needs only one W-sized snapshot)
        float* snap = (float*)d_ws;
        hipMemcpyAsync(out, W, WB, hipMemcpyDeviceToDevice, stream);
        int blocks = (Np * 64 + 255) / 256;
        pos_kernel<<<blocks, 256, 0, stream>>>(W, out, lut, ipu, ipv, Np);
        hipMemcpyAsync(snap, out, WB, hipMemcpyDeviceToDevice, stream);
        neg_kernel<<<blocks, 256, 0, stream>>>(snap, out, lut, inu, inv, Np, NEG);
    }
}